// Round 7
// baseline (793.549 us; speedup 1.0000x reference)
//
#include <hip/hip_runtime.h>
#include <math.h>

// ---------------- problem dims ----------------
static constexpr int B_   = 64;
static constexpr int H0_  = 480, W0_ = 80;
static constexpr int C0_  = 8, C1_ = 16, C2_ = 16, C3_ = 32;
static constexpr int H1_  = 160, W1_ = 40;
static constexpr int T_   = 40,  WP_ = 20;
static constexpr int IG_  = 640;
static constexpr int HID_ = 256;
static constexpr int G3_  = 768;
static constexpr int OUT_MAIN_ = B_ * T_ * 2 * HID_;

typedef __attribute__((ext_vector_type(8))) short bf16x8;
typedef __attribute__((ext_vector_type(4))) float f32x4;

__device__ inline short f2bf(float f) {
  unsigned u = __builtin_bit_cast(unsigned, f);
  u = (u + 0x7FFFu + ((u >> 16) & 1u)) >> 16;
  return (short)u;
}
__device__ inline float bf2f(short s) {
  return __builtin_bit_cast(float, ((unsigned)(unsigned short)s) << 16);
}
__device__ inline float sigm_(float x) { return 1.f / (1.f + __expf(-x)); }
__device__ inline float tanh_(float x) { return 1.f - 2.f / (1.f + __expf(2.f * x)); }

__device__ inline void split8(const float* p, bf16x8* hi, bf16x8* lo) {
  float4 u = *(const float4*)p, v = *(const float4*)(p + 4);
  float f[8] = {u.x, u.y, u.z, u.w, v.x, v.y, v.z, v.w};
  bf16x8 h, l;
#pragma unroll
  for (int i = 0; i < 8; ++i) {
    short hs = f2bf(f[i]);
    h[i] = hs;
    l[i] = f2bf(f[i] - bf2f(hs));
  }
  *hi = h; *lo = l;
}

// ======== conv0+conv1+pool: lane-resident conv1 weights ========
// Block (b, r0): pooled rows [8r0,8r0+8) x 40 cols x 16 ch. 512 threads.
// Phase B: all 8 conv0 channels -> LDS (70 KB). Phase C: thread=(c,slot);
// 72 conv1 weights live in VGPRs (no loads in loop); y0 patches broadcast
// from LDS (16 c-lanes share addresses -> conflict-free).
__global__ __launch_bounds__(512, 4) void conv01_pool(
    const float* __restrict__ img, const float* __restrict__ w0,
    const float* __restrict__ b0, const float* __restrict__ w1,
    const float* __restrict__ b1, float* __restrict__ y2) {
  __shared__ __align__(16) float im[28 * 84];      // rows 24r0-2..+25, cols -2..81
  __shared__ __align__(16) float y0t[8][26 * 84];  // rows 24r0-1..+24, col g at idx g+1
  int b = blockIdx.x / 20, r0 = blockIdx.x % 20;
  int tid = threadIdx.x;
  const float* imgb = img + (size_t)b * (H0_ * W0_);

  for (int i = tid; i < 28 * 84; i += 512) {
    int r = i / 84, col = i % 84;
    int gr = r0 * 24 - 2 + r, gc = col - 2;
    float v = 0.f;
    if (gr >= 0 && gr < H0_ && gc >= 0 && gc < W0_) v = imgb[gr * W0_ + gc];
    im[i] = v;
  }
  __syncthreads();

  // phase B: y0 (8 channels) into LDS
#pragma unroll 1
  for (int i = tid; i < 8 * 26 * 84; i += 512) {
    int ci = i / (26 * 84);
    int rem = i % (26 * 84);
    int rr = rem / 84, cc = rem % 84;
    int grow = r0 * 24 - 1 + rr;
    float v = 0.f;
    if (grow >= 0 && grow < H0_ && cc >= 1 && cc <= 80) {
      float s = b0[ci];
#pragma unroll
      for (int kh = 0; kh < 3; ++kh)
#pragma unroll
        for (int kw = 0; kw < 3; ++kw)
          s += im[(rr + kh) * 84 + cc + kw] * w0[ci * 9 + kh * 3 + kw];
      v = fmaxf(s, 0.f);
    }
    y0t[ci][rem] = v;
  }
  __syncthreads();

  // phase C: conv1 + pool, weights in VGPRs
  int c = tid & 15, slot = tid >> 4;
  int sr = slot >> 2, scg = slot & 3;   // pooled row sr, cols 10*scg..+9
  float wv[72];
#pragma unroll
  for (int i = 0; i < 72; ++i) wv[i] = w1[c * 72 + i];
  float b1c = b1[c];
  int rbase = 3 * sr;

#pragma unroll 1
  for (int j2 = 0; j2 < 10; ++j2) {
    int j = scg * 10 + j2;
    float s6[6];
#pragma unroll
    for (int p = 0; p < 6; ++p) s6[p] = 0.f;
#pragma unroll 1
    for (int ci = 0; ci < 8; ++ci) {
      float p[5][4];
#pragma unroll
      for (int rr = 0; rr < 5; ++rr) {
        const float2* ra = (const float2*)&y0t[ci][(rbase + rr) * 84 + 2 * j];
        float2 u = ra[0], v = ra[1];
        p[rr][0] = u.x; p[rr][1] = u.y; p[rr][2] = v.x; p[rr][3] = v.y;
      }
#pragma unroll
      for (int kh = 0; kh < 3; ++kh)
#pragma unroll
        for (int kw = 0; kw < 3; ++kw) {
          float w = wv[ci * 9 + kh * 3 + kw];
#pragma unroll
          for (int ph = 0; ph < 3; ++ph)
#pragma unroll
            for (int pw = 0; pw < 2; ++pw)
              s6[ph * 2 + pw] += p[ph + kh][pw + kw] * w;
        }
    }
    float m = s6[0];
#pragma unroll
    for (int p = 1; p < 6; ++p) m = fmaxf(m, s6[p]);
    y2[(((size_t)b * 16 + c) * 160 + r0 * 8 + sr) * 40 + j] = fmaxf(m + b1c, 0.f);
  }
}

// ======== fused conv2 + conv3 + pool ========
// Block (b, tp): y3 rows 8tp-1..8tp+8 computed in LDS, then conv3+pool.
// 640 threads. conv2: thread=(c16,row10,colgroup4 of 10), rolling 3x3 window,
// per-ci weights in VGPRs. conv3: as before (lane-weights from LDS).
__global__ __launch_bounds__(640, 5) void conv23_fused(
    const float* __restrict__ y2, const float* __restrict__ w2,
    const float* __restrict__ b2, const float* __restrict__ w3,
    const float* __restrict__ b3, float* __restrict__ x) {
  __shared__ __align__(16) float y2t[16 * 12 * 42];  // rows 8tp-2..+9, col g at idx g+1
  __shared__ __align__(16) float y3t[16 * 10 * 42];  // rows 8tp-1..+8, col g at idx g+1
  __shared__ __align__(16) float w3t[144 * 32];
  int b = blockIdx.x / 20, tp = blockIdx.x % 20;
  int tid = threadIdx.x;
  const float* yb = y2 + (size_t)b * (16 * 160 * 40);

  for (int i = tid; i < 16 * 12 * 42; i += 640) {
    int cc = i % 42, r = (i / 42) % 12, ci = i / (12 * 42);
    int gr = tp * 8 - 2 + r, gc = cc - 1;
    float v = 0.f;
    if (gr >= 0 && gr < 160 && gc >= 0 && gc < 40) v = yb[(ci * 160 + gr) * 40 + gc];
    y2t[i] = v;
  }
  for (int i = tid; i < 144 * 32; i += 640) {
    int k = i / 32, cc = i % 32;
    w3t[i] = w3[cc * 144 + k];
  }
  if (tid < 160) {  // zero y3t boundary cols (idx 0 and 41)
    int ci = tid / 10, r = tid % 10;
    y3t[(ci * 10 + r) * 42] = 0.f;
    y3t[(ci * 10 + r) * 42 + 41] = 0.f;
  }
  __syncthreads();

  // phase B: conv2 -> y3t
  {
    int c = tid & 15, slot = tid >> 4;    // slot 0..39
    int r = slot >> 2, q4 = slot & 3;     // y3t row r (0..9), cols 10*q4..+9
    int grow = tp * 8 - 1 + r;
    bool rv = (grow >= 0 && grow < 160);
    float acc[10];
#pragma unroll
    for (int j = 0; j < 10; ++j) acc[j] = 0.f;
    float b2c = b2[c];
#pragma unroll 1
    for (int ci = 0; ci < 16; ++ci) {
      float wv[9];
#pragma unroll
      for (int k = 0; k < 9; ++k) wv[k] = w2[(c * 16 + ci) * 9 + k];
      int base = (ci * 12 + r) * 42 + 10 * q4;
      float win[3][3];
#pragma unroll
      for (int rr = 0; rr < 3; ++rr)
#pragma unroll
        for (int k = 0; k < 3; ++k) win[rr][k] = y2t[base + rr * 42 + k];
#pragma unroll
      for (int j = 0; j < 10; ++j) {
#pragma unroll
        for (int rr = 0; rr < 3; ++rr)
#pragma unroll
          for (int k = 0; k < 3; ++k) acc[j] += win[rr][k] * wv[rr * 3 + k];
        if (j < 9) {
#pragma unroll
          for (int rr = 0; rr < 3; ++rr) {
            win[rr][0] = win[rr][1];
            win[rr][1] = win[rr][2];
            win[rr][2] = y2t[base + rr * 42 + 3 + j];
          }
        }
      }
    }
#pragma unroll
    for (int j = 0; j < 10; ++j)
      y3t[(c * 10 + r) * 42 + 10 * q4 + j + 1] = rv ? fmaxf(acc[j] + b2c, 0.f) : 0.f;
  }
  __syncthreads();

  // phase C: conv3 + pool -> x[t][b][wo][c]
#pragma unroll 1
  for (int it = 0; it < 2; ++it) {
    int wk = it * 640 + tid;   // 0..1279
    int c = wk & 31;
    int wo = (wk >> 5) % 20;
    int t2 = wk / 640;
    int t = tp * 2 + t2;
    float acc[8];
#pragma unroll
    for (int p = 0; p < 8; ++p) acc[p] = 0.f;
#pragma unroll 1
    for (int ci = 0; ci < 16; ++ci) {
      float rg[6][4];
#pragma unroll
      for (int rr = 0; rr < 6; ++rr) {
        const float2* rp = (const float2*)&y3t[(ci * 10 + 4 * t2 + rr) * 42 + 2 * wo];
        float2 u = rp[0], v = rp[1];
        rg[rr][0] = u.x; rg[rr][1] = u.y; rg[rr][2] = v.x; rg[rr][3] = v.y;
      }
#pragma unroll
      for (int kh = 0; kh < 3; ++kh)
#pragma unroll
        for (int kw = 0; kw < 3; ++kw) {
          float wv = w3t[((ci * 3 + kh) * 3 + kw) * 32 + c];
#pragma unroll
          for (int ph = 0; ph < 4; ++ph)
#pragma unroll
            for (int pw = 0; pw < 2; ++pw)
              acc[ph * 2 + pw] += rg[ph + kh][pw + kw] * wv;
        }
    }
    float m = acc[0];
#pragma unroll
    for (int p = 1; p < 8; ++p) m = fmaxf(m, acc[p]);
    x[(((size_t)t * 64 + b) * 20 + wo) * 32 + c] = fmaxf(m + b3[c], 0.f);
  }
}

// ======== gx GEMM, fp32-accurate via 3-term bf16 split MFMA ========
__global__ __launch_bounds__(256) void gemm_gx_mfma(
    const float* __restrict__ x, const float* __restrict__ wih_f,
    const float* __restrict__ wih_b, const float* __restrict__ bih_f,
    const float* __restrict__ bih_b, float* __restrict__ gx) {
  __shared__ __align__(16) short Ah[4 * 128 * 8], Al[4 * 128 * 8];
  __shared__ __align__(16) short Bh[4 * 128 * 8], Bl[4 * 128 * 8];
  int bm = blockIdx.x * 128, bn = blockIdx.y * 128, dir = blockIdx.z;
  const float* W = dir ? wih_b : wih_f;
  const float* bias = dir ? bih_b : bih_f;
  float* C = gx + (size_t)dir * (T_ * B_) * G3_;
  int tid = threadIdx.x;
  int wave = tid >> 6, lane = tid & 63, q = lane >> 4, n = lane & 15;
  int wm = (wave & 1) * 64, wn2 = (wave >> 1) * 64;
  f32x4 acc[4][4];
#pragma unroll
  for (int mi = 0; mi < 4; ++mi)
#pragma unroll
    for (int ni = 0; ni < 4; ++ni) acc[mi][ni] = (f32x4){0.f, 0.f, 0.f, 0.f};

  for (int k0 = 0; k0 < IG_; k0 += 32) {
    bf16x8 h, l;
    split8(x + (size_t)(bm + lane) * IG_ + k0 + wave * 8, &h, &l);
    *(bf16x8*)&Ah[(wave * 128 + lane) * 8] = h;
    *(bf16x8*)&Al[(wave * 128 + lane) * 8] = l;
    split8(x + (size_t)(bm + lane + 64) * IG_ + k0 + wave * 8, &h, &l);
    *(bf16x8*)&Ah[(wave * 128 + lane + 64) * 8] = h;
    *(bf16x8*)&Al[(wave * 128 + lane + 64) * 8] = l;
    split8(W + (size_t)(bn + lane) * IG_ + k0 + wave * 8, &h, &l);
    *(bf16x8*)&Bh[(wave * 128 + lane) * 8] = h;
    *(bf16x8*)&Bl[(wave * 128 + lane) * 8] = l;
    split8(W + (size_t)(bn + lane + 64) * IG_ + k0 + wave * 8, &h, &l);
    *(bf16x8*)&Bh[(wave * 128 + lane + 64) * 8] = h;
    *(bf16x8*)&Bl[(wave * 128 + lane + 64) * 8] = l;
    __syncthreads();
    bf16x8 ah[4], al[4], bh[4], bl[4];
#pragma unroll
    for (int mi = 0; mi < 4; ++mi) {
      ah[mi] = *(const bf16x8*)&Ah[(q * 128 + wm + mi * 16 + n) * 8];
      al[mi] = *(const bf16x8*)&Al[(q * 128 + wm + mi * 16 + n) * 8];
    }
#pragma unroll
    for (int ni = 0; ni < 4; ++ni) {
      bh[ni] = *(const bf16x8*)&Bh[(q * 128 + wn2 + ni * 16 + n) * 8];
      bl[ni] = *(const bf16x8*)&Bl[(q * 128 + wn2 + ni * 16 + n) * 8];
    }
#pragma unroll
    for (int mi = 0; mi < 4; ++mi)
#pragma unroll
      for (int ni = 0; ni < 4; ++ni) {
        acc[mi][ni] = __builtin_amdgcn_mfma_f32_16x16x32_bf16(
            al[mi], bh[ni], acc[mi][ni], 0, 0, 0);
        acc[mi][ni] = __builtin_amdgcn_mfma_f32_16x16x32_bf16(
            ah[mi], bl[ni], acc[mi][ni], 0, 0, 0);
        acc[mi][ni] = __builtin_amdgcn_mfma_f32_16x16x32_bf16(
            ah[mi], bh[ni], acc[mi][ni], 0, 0, 0);
      }
    __syncthreads();
  }
#pragma unroll
  for (int mi = 0; mi < 4; ++mi)
#pragma unroll
    for (int ni = 0; ni < 4; ++ni)
#pragma unroll
      for (int r = 0; r < 4; ++r) {
        int row = bm + wm + mi * 16 + q * 4 + r;
        int col = bn + wn2 + ni * 16 + n;
        C[(size_t)row * G3_ + col] = acc[mi][ni][r] + bias[col];
      }
}

// ======== weight-stationary MFMA GRU, identity-mapped LDS ========
__global__ __launch_bounds__(1024) void gru_mfma(
    const float* __restrict__ gx,
    const float* __restrict__ whh_f, const float* __restrict__ whh_b,
    const float* __restrict__ bhh_f, const float* __restrict__ bhh_b,
    const float* __restrict__ h0, float* __restrict__ out) {
  __shared__ __align__(16) short wn[32 * 256 * 8];    // 128 KB [ch][j][8]
  __shared__ __align__(16) short hb[2][32 * 16 * 8];  // 2x8 KB [ch][b][8]
  int blk = blockIdx.x, dir = blk >> 2, mb = blk & 3;
  const float* Wh  = dir ? whh_b : whh_f;
  const float* bhh = dir ? bhh_b : bhh_f;
  int tid = threadIdx.x;
  int wave = tid >> 6, lane = tid & 63, q = lane >> 4, n = lane & 15;
  int jw = wave << 4;

  for (int idx = tid; idx < 256 * 32; idx += 1024) {
    int j = idx >> 5, ch = idx & 31;
    const float* src = Wh + (size_t)(512 + j) * HID_ + ch * 8;
    float4 u = *(const float4*)src, v = *(const float4*)(src + 4);
    short* d = &wn[(ch * 256 + j) * 8];
    d[0] = f2bf(u.x); d[1] = f2bf(u.y); d[2] = f2bf(u.z); d[3] = f2bf(u.w);
    d[4] = f2bf(v.x); d[5] = f2bf(v.y); d[6] = f2bf(v.z); d[7] = f2bf(v.w);
  }
  if (tid < 512) {
    int b = tid >> 5, ch = tid & 31;
    const float* src = h0 + (size_t)(dir * 64 + mb * 16 + b) * HID_ + ch * 8;
    float4 u = *(const float4*)src, v = *(const float4*)(src + 4);
    short* d = &hb[0][(ch * 16 + b) * 8];
    d[0] = f2bf(u.x); d[1] = f2bf(u.y); d[2] = f2bf(u.z); d[3] = f2bf(u.w);
    d[4] = f2bf(v.x); d[5] = f2bf(v.y); d[6] = f2bf(v.z); d[7] = f2bf(v.w);
  }
  bf16x8 Br[8], Bz[8];
#pragma unroll
  for (int kt = 0; kt < 8; ++kt) {
    const float* pr = Wh + (size_t)(jw + n) * HID_ + kt * 32 + q * 8;
    const float* pz = Wh + (size_t)(256 + jw + n) * HID_ + kt * 32 + q * 8;
    float4 u = *(const float4*)pr, v = *(const float4*)(pr + 4);
    Br[kt] = (bf16x8){f2bf(u.x), f2bf(u.y), f2bf(u.z), f2bf(u.w),
                      f2bf(v.x), f2bf(v.y), f2bf(v.z), f2bf(v.w)};
    float4 uz = *(const float4*)pz, vz = *(const float4*)(pz + 4);
    Bz[kt] = (bf16x8){f2bf(uz.x), f2bf(uz.y), f2bf(uz.z), f2bf(uz.w),
                      f2bf(vz.x), f2bf(vz.y), f2bf(vz.z), f2bf(vz.w)};
  }
  float hold[4];
#pragma unroll
  for (int r = 0; r < 4; ++r)
    hold[r] = h0[(size_t)(dir * 64 + mb * 16 + q * 4 + r) * HID_ + jw + n];
  float bh0 = bhh[jw + n], bh1 = bhh[256 + jw + n], bh2 = bhh[512 + jw + n];
  int chc = (jw + n) >> 3, ce = (jw + n) & 7;
  __syncthreads();

  for (int s = 0; s < T_; ++s) {
    int t = dir ? (T_ - 1 - s) : s;
    const short* hc = hb[s & 1];
    short* hx = hb[(s & 1) ^ 1];
    const float* gxt = gx + ((size_t)(dir * T_ + t) * B_ + mb * 16) * G3_;
    float xr[4], xz[4], xn[4];
#pragma unroll
    for (int r = 0; r < 4; ++r) {
      const float* gxb = gxt + (size_t)(q * 4 + r) * G3_ + jw + n;
      xr[r] = gxb[0]; xz[r] = gxb[256]; xn[r] = gxb[512];
    }
    f32x4 a0 = {0.f, 0.f, 0.f, 0.f}, a1 = a0, a2 = a0;
#pragma unroll
    for (int kt = 0; kt < 8; ++kt) {
      bf16x8 af = *(const bf16x8*)&hc[((kt * 4 + q) * 16 + n) * 8];
      bf16x8 bn = *(const bf16x8*)&wn[((kt * 4 + q) * 256 + jw + n) * 8];
      a0 = __builtin_amdgcn_mfma_f32_16x16x32_bf16(af, Br[kt], a0, 0, 0, 0);
      a1 = __builtin_amdgcn_mfma_f32_16x16x32_bf16(af, Bz[kt], a1, 0, 0, 0);
      a2 = __builtin_amdgcn_mfma_f32_16x16x32_bf16(af, bn, a2, 0, 0, 0);
    }
#pragma unroll
    for (int r = 0; r < 4; ++r) {
      float rg = sigm_(xr[r] + a0[r] + bh0);
      float zg = sigm_(xz[r] + a1[r] + bh1);
      float ng = tanh_(xn[r] + rg * (a2[r] + bh2));
      float hnew = (1.f - zg) * ng + zg * hold[r];
      hold[r] = hnew;
      int gb = mb * 16 + q * 4 + r;
      out[((size_t)gb * T_ + t) * (2 * HID_) + dir * HID_ + jw + n] = hnew;
      hx[(chc * 16 + q * 4 + r) * 8 + ce] = f2bf(hnew);
    }
    __syncthreads();
  }
#pragma unroll
  for (int r = 0; r < 4; ++r)
    out[(size_t)OUT_MAIN_ + (size_t)(dir * 64 + mb * 16 + q * 4 + r) * HID_ + jw + n] = hold[r];
}

// ---------------- launch ----------------
extern "C" void kernel_launch(void* const* d_in, const int* in_sizes, int n_in,
                              void* d_out, int out_size, void* d_ws, size_t ws_size,
                              hipStream_t stream) {
  (void)in_sizes; (void)n_in; (void)out_size; (void)ws_size;
  const float* img    = (const float*)d_in[0];
  const float* hid0   = (const float*)d_in[1];
  const float* c0w    = (const float*)d_in[2];
  const float* c0b    = (const float*)d_in[3];
  const float* c1w    = (const float*)d_in[4];
  const float* c1b    = (const float*)d_in[5];
  const float* c2w    = (const float*)d_in[6];
  const float* c2b    = (const float*)d_in[7];
  const float* c3w    = (const float*)d_in[8];
  const float* c3b    = (const float*)d_in[9];
  const float* wih_f  = (const float*)d_in[10];
  const float* whh_f  = (const float*)d_in[11];
  const float* bih_f  = (const float*)d_in[12];
  const float* bhh_f  = (const float*)d_in[13];
  const float* wih_b  = (const float*)d_in[14];
  const float* whh_b  = (const float*)d_in[15];
  const float* bih_b  = (const float*)d_in[16];
  const float* bhh_b  = (const float*)d_in[17];
  float* out = (float*)d_out;

  // ws layout (float offsets): y2 6.55M | x 1.64M | gx 3.93M
  float* wsf = (float*)d_ws;
  float* y2  = wsf;
  float* x   = wsf + 6553600;
  float* gx  = wsf + 8192000;

  conv01_pool<<<64 * 20, 512, 0, stream>>>(img, c0w, c0b, c1w, c1b, y2);
  conv23_fused<<<64 * 20, 640, 0, stream>>>(y2, c2w, c2b, c3w, c3b, x);
  gemm_gx_mfma<<<dim3(20, 6, 2), 256, 0, stream>>>(x, wih_f, wih_b, bih_f, bih_b, gx);
  gru_mfma<<<8, 1024, 0, stream>>>(gx, whh_f, whh_b, bhh_f, bhh_b, hid0, out);
}

// Round 8
// 590.135 us; speedup vs baseline: 1.3447x; 1.3447x over previous
//
#include <hip/hip_runtime.h>
#include <math.h>

// ---------------- problem dims ----------------
static constexpr int B_   = 64;
static constexpr int H0_  = 480, W0_ = 80;
static constexpr int C0_  = 8, C1_ = 16, C2_ = 16, C3_ = 32;
static constexpr int H1_  = 160, W1_ = 40;
static constexpr int T_   = 40,  WP_ = 20;
static constexpr int IG_  = 640;
static constexpr int HID_ = 256;
static constexpr int G3_  = 768;
static constexpr int OUT_MAIN_ = B_ * T_ * 2 * HID_;

typedef __attribute__((ext_vector_type(8))) short bf16x8;
typedef __attribute__((ext_vector_type(4))) float f32x4;

__device__ inline short f2bf(float f) {
  unsigned u = __builtin_bit_cast(unsigned, f);
  u = (u + 0x7FFFu + ((u >> 16) & 1u)) >> 16;
  return (short)u;
}
__device__ inline float bf2f(short s) {
  return __builtin_bit_cast(float, ((unsigned)(unsigned short)s) << 16);
}
__device__ inline float sigm_(float x) { return 1.f / (1.f + __expf(-x)); }
__device__ inline float tanh_(float x) { return 1.f - 2.f / (1.f + __expf(2.f * x)); }

__device__ inline void split8(const float* p, bf16x8* hi, bf16x8* lo) {
  float4 u = *(const float4*)p, v = *(const float4*)(p + 4);
  float f[8] = {u.x, u.y, u.z, u.w, v.x, v.y, v.z, v.w};
  bf16x8 h, l;
#pragma unroll
  for (int i = 0; i < 8; ++i) {
    short hs = f2bf(f[i]);
    h[i] = hs;
    l[i] = f2bf(f[i] - bf2f(hs));
  }
  *hi = h; *lo = l;
}

// ======== conv0+conv1+pool: lane-resident conv1 weights ========
// Block (b, r0): pooled rows [8r0,8r0+8) x 40 cols x 16 ch. 512 threads.
// __launch_bounds__(512,2): 256-VGPR budget so wv[72] stays in registers
// (512,4 capped at 128 -> scratch spill -> 1.3 GB HBM traffic in round 7).
__global__ __launch_bounds__(512, 2) void conv01_pool(
    const float* __restrict__ img, const float* __restrict__ w0,
    const float* __restrict__ b0, const float* __restrict__ w1,
    const float* __restrict__ b1, float* __restrict__ y2) {
  __shared__ __align__(16) float im[28 * 84];      // rows 24r0-2..+25, cols -2..81
  __shared__ __align__(16) float y0t[8][26 * 84];  // rows 24r0-1..+24, col g at idx g+1
  int b = blockIdx.x / 20, r0 = blockIdx.x % 20;
  int tid = threadIdx.x;
  const float* imgb = img + (size_t)b * (H0_ * W0_);

  for (int i = tid; i < 28 * 84; i += 512) {
    int r = i / 84, col = i % 84;
    int gr = r0 * 24 - 2 + r, gc = col - 2;
    float v = 0.f;
    if (gr >= 0 && gr < H0_ && gc >= 0 && gc < W0_) v = imgb[gr * W0_ + gc];
    im[i] = v;
  }
  __syncthreads();

  // phase B: y0 (8 channels) into LDS
#pragma unroll 1
  for (int i = tid; i < 8 * 26 * 84; i += 512) {
    int ci = i / (26 * 84);
    int rem = i % (26 * 84);
    int rr = rem / 84, cc = rem % 84;
    int grow = r0 * 24 - 1 + rr;
    float v = 0.f;
    if (grow >= 0 && grow < H0_ && cc >= 1 && cc <= 80) {
      float s = b0[ci];
#pragma unroll
      for (int kh = 0; kh < 3; ++kh)
#pragma unroll
        for (int kw = 0; kw < 3; ++kw)
          s += im[(rr + kh) * 84 + cc + kw] * w0[ci * 9 + kh * 3 + kw];
      v = fmaxf(s, 0.f);
    }
    y0t[ci][rem] = v;
  }
  __syncthreads();

  // phase C: conv1 + pool, 72 weights per thread in VGPRs
  int c = tid & 15, slot = tid >> 4;
  int sr = slot >> 2, scg = slot & 3;   // pooled row sr, cols 10*scg..+9
  float wv[72];
#pragma unroll
  for (int i = 0; i < 18; ++i) {
    float4 w4 = *(const float4*)(w1 + c * 72 + i * 4);
    wv[i * 4 + 0] = w4.x; wv[i * 4 + 1] = w4.y;
    wv[i * 4 + 2] = w4.z; wv[i * 4 + 3] = w4.w;
  }
  float b1c = b1[c];
  int rbase = 3 * sr;

#pragma unroll 1
  for (int j2 = 0; j2 < 10; ++j2) {
    int j = scg * 10 + j2;
    float s6[6];
#pragma unroll
    for (int p = 0; p < 6; ++p) s6[p] = 0.f;
#pragma unroll
    for (int ci = 0; ci < 8; ++ci) {
      float p[5][4];
#pragma unroll
      for (int rr = 0; rr < 5; ++rr) {
        const float2* ra = (const float2*)&y0t[ci][(rbase + rr) * 84 + 2 * j];
        float2 u = ra[0], v = ra[1];
        p[rr][0] = u.x; p[rr][1] = u.y; p[rr][2] = v.x; p[rr][3] = v.y;
      }
#pragma unroll
      for (int kh = 0; kh < 3; ++kh)
#pragma unroll
        for (int kw = 0; kw < 3; ++kw) {
          float w = wv[ci * 9 + kh * 3 + kw];
#pragma unroll
          for (int ph = 0; ph < 3; ++ph)
#pragma unroll
            for (int pw = 0; pw < 2; ++pw)
              s6[ph * 2 + pw] += p[ph + kh][pw + kw] * w;
        }
    }
    float m = s6[0];
#pragma unroll
    for (int p = 1; p < 6; ++p) m = fmaxf(m, s6[p]);
    y2[(((size_t)b * 16 + c) * 160 + r0 * 8 + sr) * 40 + j] = fmaxf(m + b1c, 0.f);
  }
}

// ======== fused conv2 + conv3 + pool ========
__global__ __launch_bounds__(640, 5) void conv23_fused(
    const float* __restrict__ y2, const float* __restrict__ w2,
    const float* __restrict__ b2, const float* __restrict__ w3,
    const float* __restrict__ b3, float* __restrict__ x) {
  __shared__ __align__(16) float y2t[16 * 12 * 42];  // rows 8tp-2..+9, col g at idx g+1
  __shared__ __align__(16) float y3t[16 * 10 * 42];  // rows 8tp-1..+8, col g at idx g+1
  __shared__ __align__(16) float w3t[144 * 32];
  int b = blockIdx.x / 20, tp = blockIdx.x % 20;
  int tid = threadIdx.x;
  const float* yb = y2 + (size_t)b * (16 * 160 * 40);

  for (int i = tid; i < 16 * 12 * 42; i += 640) {
    int cc = i % 42, r = (i / 42) % 12, ci = i / (12 * 42);
    int gr = tp * 8 - 2 + r, gc = cc - 1;
    float v = 0.f;
    if (gr >= 0 && gr < 160 && gc >= 0 && gc < 40) v = yb[(ci * 160 + gr) * 40 + gc];
    y2t[i] = v;
  }
  for (int i = tid; i < 144 * 32; i += 640) {
    int k = i / 32, cc = i % 32;
    w3t[i] = w3[cc * 144 + k];
  }
  if (tid < 160) {
    int ci = tid / 10, r = tid % 10;
    y3t[(ci * 10 + r) * 42] = 0.f;
    y3t[(ci * 10 + r) * 42 + 41] = 0.f;
  }
  __syncthreads();

  // phase B: conv2 -> y3t
  {
    int c = tid & 15, slot = tid >> 4;
    int r = slot >> 2, q4 = slot & 3;
    int grow = tp * 8 - 1 + r;
    bool rv = (grow >= 0 && grow < 160);
    float acc[10];
#pragma unroll
    for (int j = 0; j < 10; ++j) acc[j] = 0.f;
    float b2c = b2[c];
#pragma unroll 1
    for (int ci = 0; ci < 16; ++ci) {
      float wv[9];
#pragma unroll
      for (int k = 0; k < 9; ++k) wv[k] = w2[(c * 16 + ci) * 9 + k];
      int base = (ci * 12 + r) * 42 + 10 * q4;
      float win[3][3];
#pragma unroll
      for (int rr = 0; rr < 3; ++rr)
#pragma unroll
        for (int k = 0; k < 3; ++k) win[rr][k] = y2t[base + rr * 42 + k];
#pragma unroll
      for (int j = 0; j < 10; ++j) {
#pragma unroll
        for (int rr = 0; rr < 3; ++rr)
#pragma unroll
          for (int k = 0; k < 3; ++k) acc[j] += win[rr][k] * wv[rr * 3 + k];
        if (j < 9) {
#pragma unroll
          for (int rr = 0; rr < 3; ++rr) {
            win[rr][0] = win[rr][1];
            win[rr][1] = win[rr][2];
            win[rr][2] = y2t[base + rr * 42 + 3 + j];
          }
        }
      }
    }
#pragma unroll
    for (int j = 0; j < 10; ++j)
      y3t[(c * 10 + r) * 42 + 10 * q4 + j + 1] = rv ? fmaxf(acc[j] + b2c, 0.f) : 0.f;
  }
  __syncthreads();

  // phase C: conv3 + pool -> x[t][b][wo][c]
#pragma unroll 1
  for (int it = 0; it < 2; ++it) {
    int wk = it * 640 + tid;
    int c = wk & 31;
    int wo = (wk >> 5) % 20;
    int t2 = wk / 640;
    int t = tp * 2 + t2;
    float acc[8];
#pragma unroll
    for (int p = 0; p < 8; ++p) acc[p] = 0.f;
#pragma unroll 1
    for (int ci = 0; ci < 16; ++ci) {
      float rg[6][4];
#pragma unroll
      for (int rr = 0; rr < 6; ++rr) {
        const float2* rp = (const float2*)&y3t[(ci * 10 + 4 * t2 + rr) * 42 + 2 * wo];
        float2 u = rp[0], v = rp[1];
        rg[rr][0] = u.x; rg[rr][1] = u.y; rg[rr][2] = v.x; rg[rr][3] = v.y;
      }
#pragma unroll
      for (int kh = 0; kh < 3; ++kh)
#pragma unroll
        for (int kw = 0; kw < 3; ++kw) {
          float wv = w3t[((ci * 3 + kh) * 3 + kw) * 32 + c];
#pragma unroll
          for (int ph = 0; ph < 4; ++ph)
#pragma unroll
            for (int pw = 0; pw < 2; ++pw)
              acc[ph * 2 + pw] += rg[ph + kh][pw + kw] * wv;
        }
    }
    float m = acc[0];
#pragma unroll
    for (int p = 1; p < 8; ++p) m = fmaxf(m, acc[p]);
    x[(((size_t)t * 64 + b) * 20 + wo) * 32 + c] = fmaxf(m + b3[c], 0.f);
  }
}

// ======== gx GEMM, fp32-accurate via 3-term bf16 split MFMA ========
__global__ __launch_bounds__(256) void gemm_gx_mfma(
    const float* __restrict__ x, const float* __restrict__ wih_f,
    const float* __restrict__ wih_b, const float* __restrict__ bih_f,
    const float* __restrict__ bih_b, float* __restrict__ gx) {
  __shared__ __align__(16) short Ah[4 * 128 * 8], Al[4 * 128 * 8];
  __shared__ __align__(16) short Bh[4 * 128 * 8], Bl[4 * 128 * 8];
  int bm = blockIdx.x * 128, bn = blockIdx.y * 128, dir = blockIdx.z;
  const float* W = dir ? wih_b : wih_f;
  const float* bias = dir ? bih_b : bih_f;
  float* C = gx + (size_t)dir * (T_ * B_) * G3_;
  int tid = threadIdx.x;
  int wave = tid >> 6, lane = tid & 63, q = lane >> 4, n = lane & 15;
  int wm = (wave & 1) * 64, wn2 = (wave >> 1) * 64;
  f32x4 acc[4][4];
#pragma unroll
  for (int mi = 0; mi < 4; ++mi)
#pragma unroll
    for (int ni = 0; ni < 4; ++ni) acc[mi][ni] = (f32x4){0.f, 0.f, 0.f, 0.f};

  for (int k0 = 0; k0 < IG_; k0 += 32) {
    bf16x8 h, l;
    split8(x + (size_t)(bm + lane) * IG_ + k0 + wave * 8, &h, &l);
    *(bf16x8*)&Ah[(wave * 128 + lane) * 8] = h;
    *(bf16x8*)&Al[(wave * 128 + lane) * 8] = l;
    split8(x + (size_t)(bm + lane + 64) * IG_ + k0 + wave * 8, &h, &l);
    *(bf16x8*)&Ah[(wave * 128 + lane + 64) * 8] = h;
    *(bf16x8*)&Al[(wave * 128 + lane + 64) * 8] = l;
    split8(W + (size_t)(bn + lane) * IG_ + k0 + wave * 8, &h, &l);
    *(bf16x8*)&Bh[(wave * 128 + lane) * 8] = h;
    *(bf16x8*)&Bl[(wave * 128 + lane) * 8] = l;
    split8(W + (size_t)(bn + lane + 64) * IG_ + k0 + wave * 8, &h, &l);
    *(bf16x8*)&Bh[(wave * 128 + lane + 64) * 8] = h;
    *(bf16x8*)&Bl[(wave * 128 + lane + 64) * 8] = l;
    __syncthreads();
    bf16x8 ah[4], al[4], bh[4], bl[4];
#pragma unroll
    for (int mi = 0; mi < 4; ++mi) {
      ah[mi] = *(const bf16x8*)&Ah[(q * 128 + wm + mi * 16 + n) * 8];
      al[mi] = *(const bf16x8*)&Al[(q * 128 + wm + mi * 16 + n) * 8];
    }
#pragma unroll
    for (int ni = 0; ni < 4; ++ni) {
      bh[ni] = *(const bf16x8*)&Bh[(q * 128 + wn2 + ni * 16 + n) * 8];
      bl[ni] = *(const bf16x8*)&Bl[(q * 128 + wn2 + ni * 16 + n) * 8];
    }
#pragma unroll
    for (int mi = 0; mi < 4; ++mi)
#pragma unroll
      for (int ni = 0; ni < 4; ++ni) {
        acc[mi][ni] = __builtin_amdgcn_mfma_f32_16x16x32_bf16(
            al[mi], bh[ni], acc[mi][ni], 0, 0, 0);
        acc[mi][ni] = __builtin_amdgcn_mfma_f32_16x16x32_bf16(
            ah[mi], bl[ni], acc[mi][ni], 0, 0, 0);
        acc[mi][ni] = __builtin_amdgcn_mfma_f32_16x16x32_bf16(
            ah[mi], bh[ni], acc[mi][ni], 0, 0, 0);
      }
    __syncthreads();
  }
#pragma unroll
  for (int mi = 0; mi < 4; ++mi)
#pragma unroll
    for (int ni = 0; ni < 4; ++ni)
#pragma unroll
      for (int r = 0; r < 4; ++r) {
        int row = bm + wm + mi * 16 + q * 4 + r;
        int col = bn + wn2 + ni * 16 + n;
        C[(size_t)row * G3_ + col] = acc[mi][ni][r] + bias[col];
      }
}

// ======== weight-stationary MFMA GRU, identity-mapped LDS ========
__global__ __launch_bounds__(1024) void gru_mfma(
    const float* __restrict__ gx,
    const float* __restrict__ whh_f, const float* __restrict__ whh_b,
    const float* __restrict__ bhh_f, const float* __restrict__ bhh_b,
    const float* __restrict__ h0, float* __restrict__ out) {
  __shared__ __align__(16) short wn[32 * 256 * 8];    // 128 KB [ch][j][8]
  __shared__ __align__(16) short hb[2][32 * 16 * 8];  // 2x8 KB [ch][b][8]
  int blk = blockIdx.x, dir = blk >> 2, mb = blk & 3;
  const float* Wh  = dir ? whh_b : whh_f;
  const float* bhh = dir ? bhh_b : bhh_f;
  int tid = threadIdx.x;
  int wave = tid >> 6, lane = tid & 63, q = lane >> 4, n = lane & 15;
  int jw = wave << 4;

  for (int idx = tid; idx < 256 * 32; idx += 1024) {
    int j = idx >> 5, ch = idx & 31;
    const float* src = Wh + (size_t)(512 + j) * HID_ + ch * 8;
    float4 u = *(const float4*)src, v = *(const float4*)(src + 4);
    short* d = &wn[(ch * 256 + j) * 8];
    d[0] = f2bf(u.x); d[1] = f2bf(u.y); d[2] = f2bf(u.z); d[3] = f2bf(u.w);
    d[4] = f2bf(v.x); d[5] = f2bf(v.y); d[6] = f2bf(v.z); d[7] = f2bf(v.w);
  }
  if (tid < 512) {
    int b = tid >> 5, ch = tid & 31;
    const float* src = h0 + (size_t)(dir * 64 + mb * 16 + b) * HID_ + ch * 8;
    float4 u = *(const float4*)src, v = *(const float4*)(src + 4);
    short* d = &hb[0][(ch * 16 + b) * 8];
    d[0] = f2bf(u.x); d[1] = f2bf(u.y); d[2] = f2bf(u.z); d[3] = f2bf(u.w);
    d[4] = f2bf(v.x); d[5] = f2bf(v.y); d[6] = f2bf(v.z); d[7] = f2bf(v.w);
  }
  bf16x8 Br[8], Bz[8];
#pragma unroll
  for (int kt = 0; kt < 8; ++kt) {
    const float* pr = Wh + (size_t)(jw + n) * HID_ + kt * 32 + q * 8;
    const float* pz = Wh + (size_t)(256 + jw + n) * HID_ + kt * 32 + q * 8;
    float4 u = *(const float4*)pr, v = *(const float4*)(pr + 4);
    Br[kt] = (bf16x8){f2bf(u.x), f2bf(u.y), f2bf(u.z), f2bf(u.w),
                      f2bf(v.x), f2bf(v.y), f2bf(v.z), f2bf(v.w)};
    float4 uz = *(const float4*)pz, vz = *(const float4*)(pz + 4);
    Bz[kt] = (bf16x8){f2bf(uz.x), f2bf(uz.y), f2bf(uz.z), f2bf(uz.w),
                      f2bf(vz.x), f2bf(vz.y), f2bf(vz.z), f2bf(vz.w)};
  }
  float hold[4];
#pragma unroll
  for (int r = 0; r < 4; ++r)
    hold[r] = h0[(size_t)(dir * 64 + mb * 16 + q * 4 + r) * HID_ + jw + n];
  float bh0 = bhh[jw + n], bh1 = bhh[256 + jw + n], bh2 = bhh[512 + jw + n];
  int chc = (jw + n) >> 3, ce = (jw + n) & 7;
  __syncthreads();

  for (int s = 0; s < T_; ++s) {
    int t = dir ? (T_ - 1 - s) : s;
    const short* hc = hb[s & 1];
    short* hx = hb[(s & 1) ^ 1];
    const float* gxt = gx + ((size_t)(dir * T_ + t) * B_ + mb * 16) * G3_;
    float xr[4], xz[4], xn[4];
#pragma unroll
    for (int r = 0; r < 4; ++r) {
      const float* gxb = gxt + (size_t)(q * 4 + r) * G3_ + jw + n;
      xr[r] = gxb[0]; xz[r] = gxb[256]; xn[r] = gxb[512];
    }
    f32x4 a0 = {0.f, 0.f, 0.f, 0.f}, a1 = a0, a2 = a0;
#pragma unroll
    for (int kt = 0; kt < 8; ++kt) {
      bf16x8 af = *(const bf16x8*)&hc[((kt * 4 + q) * 16 + n) * 8];
      bf16x8 bn = *(const bf16x8*)&wn[((kt * 4 + q) * 256 + jw + n) * 8];
      a0 = __builtin_amdgcn_mfma_f32_16x16x32_bf16(af, Br[kt], a0, 0, 0, 0);
      a1 = __builtin_amdgcn_mfma_f32_16x16x32_bf16(af, Bz[kt], a1, 0, 0, 0);
      a2 = __builtin_amdgcn_mfma_f32_16x16x32_bf16(af, bn, a2, 0, 0, 0);
    }
#pragma unroll
    for (int r = 0; r < 4; ++r) {
      float rg = sigm_(xr[r] + a0[r] + bh0);
      float zg = sigm_(xz[r] + a1[r] + bh1);
      float ng = tanh_(xn[r] + rg * (a2[r] + bh2));
      float hnew = (1.f - zg) * ng + zg * hold[r];
      hold[r] = hnew;
      int gb = mb * 16 + q * 4 + r;
      out[((size_t)gb * T_ + t) * (2 * HID_) + dir * HID_ + jw + n] = hnew;
      hx[(chc * 16 + q * 4 + r) * 8 + ce] = f2bf(hnew);
    }
    __syncthreads();
  }
#pragma unroll
  for (int r = 0; r < 4; ++r)
    out[(size_t)OUT_MAIN_ + (size_t)(dir * 64 + mb * 16 + q * 4 + r) * HID_ + jw + n] = hold[r];
}

// ---------------- launch ----------------
extern "C" void kernel_launch(void* const* d_in, const int* in_sizes, int n_in,
                              void* d_out, int out_size, void* d_ws, size_t ws_size,
                              hipStream_t stream) {
  (void)in_sizes; (void)n_in; (void)out_size; (void)ws_size;
  const float* img    = (const float*)d_in[0];
  const float* hid0   = (const float*)d_in[1];
  const float* c0w    = (const float*)d_in[2];
  const float* c0b    = (const float*)d_in[3];
  const float* c1w    = (const float*)d_in[4];
  const float* c1b    = (const float*)d_in[5];
  const float* c2w    = (const float*)d_in[6];
  const float* c2b    = (const float*)d_in[7];
  const float* c3w    = (const float*)d_in[8];
  const float* c3b    = (const float*)d_in[9];
  const float* wih_f  = (const float*)d_in[10];
  const float* whh_f  = (const float*)d_in[11];
  const float* bih_f  = (const float*)d_in[12];
  const float* bhh_f  = (const float*)d_in[13];
  const float* wih_b  = (const float*)d_in[14];
  const float* whh_b  = (const float*)d_in[15];
  const float* bih_b  = (const float*)d_in[16];
  const float* bhh_b  = (const float*)d_in[17];
  float* out = (float*)d_out;

  float* wsf = (float*)d_ws;
  float* y2  = wsf;
  float* x   = wsf + 6553600;
  float* gx  = wsf + 8192000;

  conv01_pool<<<64 * 20, 512, 0, stream>>>(img, c0w, c0b, c1w, c1b, y2);
  conv23_fused<<<64 * 20, 640, 0, stream>>>(y2, c2w, c2b, c3w, c3b, x);
  gemm_gx_mfma<<<dim3(20, 6, 2), 256, 0, stream>>>(x, wih_f, wih_b, bih_f, bih_b, gx);
  gru_mfma<<<8, 1024, 0, stream>>>(gx, whh_f, whh_b, bhh_f, bhh_b, hid0, out);
}